// Round 4
// baseline (284.376 us; speedup 1.0000x reference)
//
#include <hip/hip_runtime.h>
#include <math.h>

// ---------------------------------------------------------------------------
// QualityGatedMamba: x(B,T,1024) -> out(B,T,1024).
// Round 3: double-buffered prefetch GEMM (T3-minimum), bf16 xz/u intermediates.
// ---------------------------------------------------------------------------

constexpr int D_MODEL = 1024;
constexpr int D_STATE = 16;
constexpr int D_CONV  = 4;
constexpr int D_INNER = 2048;
constexpr int XPROJ_W = 96;          // only first 32 cols used
constexpr int B_SZ = 2, T_LEN = 2048;
constexpr int ROWS = B_SZ * T_LEN;   // 4096
constexpr int NCHUNK = 32, CHUNK = T_LEN / NCHUNK;

enum { EPI_NONE = 0, EPI_DELTA = 1 };

typedef unsigned short ushort_t;
typedef __bf16 bf16x8 __attribute__((ext_vector_type(8)));
typedef float f32x4 __attribute__((ext_vector_type(4)));

__device__ __forceinline__ ushort_t f2bf(float f) {
  unsigned int u = __float_as_uint(f);
  u = (u + 0x7fffu + ((u >> 16) & 1u)) >> 16;   // RNE
  return (ushort_t)u;
}
__device__ __forceinline__ float bf2f(ushort_t h) {
  return __uint_as_float(((unsigned int)h) << 16);
}

__device__ __forceinline__ void gload16(const void* g, void* l) {
  __builtin_amdgcn_global_load_lds(
      (const __attribute__((address_space(1))) void*)g,
      (__attribute__((address_space(3))) void*)l, 16, 0, 0);
}

// ---------------- f32 -> bf16 elementwise -----------------------------------
__global__ __launch_bounds__(256)
void cvt_bf16_kernel(const float* __restrict__ in, ushort_t* __restrict__ out,
                     int n4)
{
  const int i = blockIdx.x * 256 + threadIdx.x;
  if (i >= n4) return;
  const float4 v = ((const float4*)in)[i];
  ushort_t tmp[4] = {f2bf(v.x), f2bf(v.y), f2bf(v.z), f2bf(v.w)};
  ((uint2*)out)[i] = *(const uint2*)tmp;
}

// ---------------- f32 (RxC) -> bf16 transposed (CxR) ------------------------
__global__ __launch_bounds__(256)
void transpose_bf16_kernel(const float* __restrict__ in,
                           ushort_t* __restrict__ out, int R, int C)
{
  __shared__ float tile[32][33];
  const int c0 = blockIdx.x * 32, r0 = blockIdx.y * 32;
  const int tx = threadIdx.x & 31, ty = threadIdx.x >> 5;   // 32 x 8
#pragma unroll
  for (int i = 0; i < 32; i += 8)
    tile[ty + i][tx] = in[(size_t)(r0 + ty + i) * C + c0 + tx];
  __syncthreads();
#pragma unroll
  for (int i = 0; i < 32; i += 8)
    out[(size_t)(c0 + ty + i) * R + r0 + tx] = f2bf(tile[tx][ty + i]);
}

// ---------------- MFMA GEMM: C(MxN) = A(MxK) @ Bt(NxK)^T --------------------
// 128x128 tile, BK=32, 4 waves of 64x64; double-buffered LDS with prefetch:
// per K-tile: STAGE(next) -> ds_read+MFMA(cur) -> vmcnt(0) -> s_barrier.
__device__ __forceinline__ void stage_tile(const ushort_t* Ag,
                                           const ushort_t* Bg,
                                           ushort_t* asb, ushort_t* bsb,
                                           int K)
{
  gload16(Ag, asb);
  gload16(Ag + (size_t)16 * K, asb + 16 * 32);
  gload16(Bg, bsb);
  gload16(Bg + (size_t)16 * K, bsb + 16 * 32);
}

template <int EPI, int OUT_BF16>
__global__ __launch_bounds__(256)
void gemm_mfma(const ushort_t* __restrict__ A, const ushort_t* __restrict__ Bt,
               void* __restrict__ Cout, int M, int N, int K,
               const float* __restrict__ bias,
               const float* __restrict__ sigma2,
               const float* __restrict__ alphap)
{
  __shared__ __align__(16) ushort_t As[2][128 * 32];
  __shared__ __align__(16) ushort_t Bs[2][128 * 32];
  const int tid = threadIdx.x;
  const int wave = tid >> 6, lane = tid & 63;
  const int lc = lane & 15, lr = lane >> 4;
  const int m0 = blockIdx.y * 128, n0 = blockIdx.x * 128;
  const int wm = wave >> 1, wn = wave & 1;

  f32x4 acc[4][4];
#pragma unroll
  for (int i = 0; i < 4; ++i)
#pragma unroll
    for (int j = 0; j < 4; ++j) acc[i][j] = (f32x4)0.f;

  const int srow = wave * 32 + (lane >> 2);
  const int skcol = (lane & 3) * 8;
  const ushort_t* Ag = A + (size_t)(m0 + srow) * K + skcol;
  const ushort_t* Bg = Bt + (size_t)(n0 + srow) * K + skcol;
  const int woff = wave * 32 * 32;   // wave's 32-row LDS region

  const int KT = K >> 5;
  // prologue: stage tile 0 into buf 0, drain, barrier
  stage_tile(Ag, Bg, &As[0][woff], &Bs[0][woff], K);
  asm volatile("s_waitcnt vmcnt(0)" ::: "memory");
  __builtin_amdgcn_s_barrier();

  int cur = 0;
  for (int kt = 0; kt < KT; ++kt) {
    const int kt1 = kt + 1;
    if (kt1 < KT)      // issue next tile's loads into the other buffer
      stage_tile(Ag + kt1 * 32, Bg + kt1 * 32,
                 &As[cur ^ 1][woff], &Bs[cur ^ 1][woff], K);
    asm volatile("" ::: "memory");
    bf16x8 af[4], bfr[4];
#pragma unroll
    for (int mi = 0; mi < 4; ++mi)
      af[mi] = *(const bf16x8*)
          &As[cur][(wm * 64 + mi * 16 + lc) * 32 + lr * 8];
#pragma unroll
    for (int ni = 0; ni < 4; ++ni)
      bfr[ni] = *(const bf16x8*)
          &Bs[cur][(wn * 64 + ni * 16 + lc) * 32 + lr * 8];
#pragma unroll
    for (int mi = 0; mi < 4; ++mi)
#pragma unroll
      for (int ni = 0; ni < 4; ++ni)
        acc[mi][ni] = __builtin_amdgcn_mfma_f32_16x16x32_bf16(
            af[mi], bfr[ni], acc[mi][ni], 0, 0, 0);
    asm volatile("" ::: "memory");
    asm volatile("s_waitcnt vmcnt(0)" ::: "memory");  // next tile landed
    __builtin_amdgcn_s_barrier();                     // all waves done reading
    cur ^= 1;
  }

  const float alphaV = (EPI == EPI_DELTA) ? alphap[0] : 0.f;
#pragma unroll
  for (int mi = 0; mi < 4; ++mi) {
    const int rowb = m0 + wm * 64 + mi * 16 + lr * 4;
#pragma unroll
    for (int ni = 0; ni < 4; ++ni) {
      const int col = n0 + wn * 64 + ni * 16 + lc;
      f32x4 v = acc[mi][ni];
#pragma unroll
      for (int r = 0; r < 4; ++r) {
        float val = v[r];
        if (EPI == EPI_DELTA) {
          const float xv = val + bias[col];
          const float sp = (xv > 20.f) ? xv : log1pf(__expf(xv));
          val = sp * __expf(-alphaV * sigma2[rowb + r]);
        }
        if (OUT_BF16)
          ((ushort_t*)Cout)[(size_t)(rowb + r) * N + col] = f2bf(val);
        else
          ((float*)Cout)[(size_t)(rowb + r) * N + col] = val;
      }
    }
  }
}

// ---------------- fused conv(k=4)+SiLU+xproj, 8 rows per block --------------
// xz is bf16 (4096 cols); u-half = cols 0..2047. u written bf16.
__global__ __launch_bounds__(256)
void conv_xproj_kernel(const ushort_t* __restrict__ xzb,
                       const float* __restrict__ cw,
                       const float* __restrict__ cb,
                       const float* __restrict__ Wx,
                       ushort_t* __restrict__ u, float* __restrict__ BC)
{
  __shared__ float us[8][D_INNER];          // 64 KB
  __shared__ float red[8][8][32];           //  8 KB
  const int tid = threadIdx.x;
  const int b = blockIdx.y;
  const int t0 = blockIdx.x * 8;
  const int ch0 = tid * 8;                  // 8 contiguous channels / thread

  float wtk[4][8], bs[8];
#pragma unroll
  for (int k = 0; k < 4; ++k) {
    float4 wa = *(const float4*)&cw[k * D_INNER + ch0];
    float4 wb = *(const float4*)&cw[k * D_INNER + ch0 + 4];
    wtk[k][0] = wa.x; wtk[k][1] = wa.y; wtk[k][2] = wa.z; wtk[k][3] = wa.w;
    wtk[k][4] = wb.x; wtk[k][5] = wb.y; wtk[k][6] = wb.z; wtk[k][7] = wb.w;
  }
  {
    float4 ba = *(const float4*)&cb[ch0];
    float4 bb = *(const float4*)&cb[ch0 + 4];
    bs[0] = ba.x; bs[1] = ba.y; bs[2] = ba.z; bs[3] = ba.w;
    bs[4] = bb.x; bs[5] = bb.y; bs[6] = bb.z; bs[7] = bb.w;
  }

#pragma unroll
  for (int r = 0; r < 8; ++r) {
    const int t = t0 + r;
    float acc[8];
#pragma unroll
    for (int j = 0; j < 8; ++j) acc[j] = bs[j];
#pragma unroll
    for (int k = 0; k < 4; ++k) {
      const int tt = t + k - 3;
      if (tt >= 0) {
        uint4 raw = *(const uint4*)
            &xzb[(size_t)(b * T_LEN + tt) * (2 * D_INNER) + ch0];
        const ushort_t* hp = (const ushort_t*)&raw;
#pragma unroll
        for (int j = 0; j < 8; ++j)
          acc[j] = fmaf(bf2f(hp[j]), wtk[k][j], acc[j]);
      }
    }
    ushort_t ub[8];
#pragma unroll
    for (int j = 0; j < 8; ++j) {
      const float s = acc[j] / (1.f + __expf(-acc[j]));
      us[r][ch0 + j] = s;
      ub[j] = f2bf(s);
    }
    *(uint4*)&u[(size_t)(b * T_LEN + t) * D_INNER + ch0] = *(const uint4*)ub;
  }
  __syncthreads();

  const int j = tid & 31, chunk = tid >> 5;
  float p[8] = {0.f, 0.f, 0.f, 0.f, 0.f, 0.f, 0.f, 0.f};
  const float* WxC = Wx + j;
  for (int i = 0; i < 256; ++i) {
    const int k = chunk * 256 + i;
    const float w = WxC[(size_t)k * XPROJ_W];
#pragma unroll
    for (int r = 0; r < 8; ++r) p[r] = fmaf(us[r][k], w, p[r]);
  }
#pragma unroll
  for (int r = 0; r < 8; ++r) red[r][chunk][j] = p[r];
  __syncthreads();
  {
    const int r = tid >> 5, jj = tid & 31;
    float s = 0.f;
#pragma unroll
    for (int c = 0; c < 8; ++c) s += red[r][c][jj];
    BC[(size_t)(b * T_LEN + t0 + r) * 32 + jj] = s;
  }
}

// ---------------- scan phase 1 ----------------------------------------------
__global__ __launch_bounds__(256)
void scan1_kernel(const float* __restrict__ delta, const ushort_t* __restrict__ u,
                  const float* __restrict__ BC, const float* __restrict__ A_log,
                  float* __restrict__ hEnd, float* __restrict__ sumD)
{
  const int c = blockIdx.x * 256 + threadIdx.x;
  const int b = blockIdx.y;
  const int j = blockIdx.z;
  float a[D_STATE], h[D_STATE];
#pragma unroll
  for (int n = 0; n < D_STATE; ++n) {
    a[n] = -__expf(A_log[c * D_STATE + n]);
    h[n] = 0.f;
  }
  float sd = 0.f;
  const int t0 = j * CHUNK;
  for (int t = t0; t < t0 + CHUNK; ++t) {
    const int row = b * T_LEN + t;
    const float d = delta[(size_t)row * D_INNER + c];
    const float uu = bf2f(u[(size_t)row * D_INNER + c]);
    sd += d;
    const float du = d * uu;
    const float4* bp4 = (const float4*)&BC[(size_t)row * 32];
    float4 b0 = bp4[0], b1 = bp4[1], b2 = bp4[2], b3 = bp4[3];
    const float bp[16] = {b0.x, b0.y, b0.z, b0.w, b1.x, b1.y, b1.z, b1.w,
                          b2.x, b2.y, b2.z, b2.w, b3.x, b3.y, b3.z, b3.w};
#pragma unroll
    for (int n = 0; n < D_STATE; ++n)
      h[n] = fmaf(__expf(d * a[n]), h[n], du * bp[n]);
  }
  const size_t base = ((size_t)b * D_INNER + c) * NCHUNK + j;
#pragma unroll
  for (int n = 0; n < D_STATE; ++n) hEnd[base * 16 + n] = h[n];
  sumD[base] = sd;
}

// ---------------- scan phase 2 ----------------------------------------------
__global__ __launch_bounds__(256)
void scan2_kernel(const float* __restrict__ A_log, float* __restrict__ hEnd,
                  const float* __restrict__ sumD)
{
  const int idx = blockIdx.x * 256 + threadIdx.x;
  const int n = idx & 15;
  const int c = (idx >> 4) & (D_INNER - 1);
  const int b = idx >> 15;
  const float an = -__expf(A_log[c * 16 + n]);
  float H = 0.f;
  for (int j = 0; j < NCHUNK; ++j) {
    const size_t base = ((size_t)b * D_INNER + c) * NCHUNK + j;
    const float he = hEnd[base * 16 + n];
    const float sd = sumD[base];
    hEnd[base * 16 + n] = H;
    H = fmaf(__expf(an * sd), H, he);
  }
}

// ---------------- scan phase 3: rescan + gate, write y as bf16 --------------
__global__ __launch_bounds__(256)
void scan3_kernel(const float* __restrict__ delta, const ushort_t* __restrict__ u,
                  const float* __restrict__ BC, const float* __restrict__ A_log,
                  const float* __restrict__ hStart,
                  const ushort_t* __restrict__ xzb,
                  const float* __restrict__ Dp, ushort_t* __restrict__ yb)
{
  const int c = blockIdx.x * 256 + threadIdx.x;
  const int b = blockIdx.y;
  const int j = blockIdx.z;
  float a[D_STATE], h[D_STATE];
  const size_t base = ((size_t)b * D_INNER + c) * NCHUNK + j;
#pragma unroll
  for (int n = 0; n < D_STATE; ++n) {
    a[n] = -__expf(A_log[c * D_STATE + n]);
    h[n] = hStart[base * 16 + n];
  }
  const float dpc = Dp[c];
  const int t0 = j * CHUNK;
  for (int t = t0; t < t0 + CHUNK; ++t) {
    const int row = b * T_LEN + t;
    const float d = delta[(size_t)row * D_INNER + c];
    const float uu = bf2f(u[(size_t)row * D_INNER + c]);
    const float du = d * uu;
    const float4* bc4 = (const float4*)&BC[(size_t)row * 32];
    float4 b0 = bc4[0], b1 = bc4[1], b2 = bc4[2], b3 = bc4[3];
    float4 c0 = bc4[4], c1 = bc4[5], c2 = bc4[6], c3 = bc4[7];
    const float bp[16] = {b0.x, b0.y, b0.z, b0.w, b1.x, b1.y, b1.z, b1.w,
                          b2.x, b2.y, b2.z, b2.w, b3.x, b3.y, b3.z, b3.w};
    const float cp[16] = {c0.x, c0.y, c0.z, c0.w, c1.x, c1.y, c1.z, c1.w,
                          c2.x, c2.y, c2.z, c2.w, c3.x, c3.y, c3.z, c3.w};
    float y = 0.f;
#pragma unroll
    for (int n = 0; n < D_STATE; ++n) {
      h[n] = fmaf(__expf(d * a[n]), h[n], du * bp[n]);
      y = fmaf(h[n], cp[n], y);
    }
    y = fmaf(uu, dpc, y);
    const float z = bf2f(xzb[(size_t)row * (2 * D_INNER) + D_INNER + c]);
    y *= z / (1.f + __expf(-z));
    yb[(size_t)row * D_INNER + c] = f2bf(y);
  }
}

// ---------------------------------------------------------------------------
extern "C" void kernel_launch(void* const* d_in, const int* in_sizes, int n_in,
                              void* d_out, int out_size, void* d_ws,
                              size_t ws_size, hipStream_t stream)
{
  const float* x       = (const float*)d_in[0];
  const float* sigma2  = (const float*)d_in[1];
  const float* W_in    = (const float*)d_in[2];
  const float* conv_w  = (const float*)d_in[3];
  const float* conv_b  = (const float*)d_in[4];
  const float* W_xproj = (const float*)d_in[5];
  const float* W_delta = (const float*)d_in[6];
  const float* b_delta = (const float*)d_in[7];
  const float* A_log   = (const float*)d_in[8];
  const float* D_param = (const float*)d_in[9];
  const float* W_out   = (const float*)d_in[10];
  const float* alpha   = (const float*)d_in[11];
  float* out = (float*)d_out;

  char* ws = (char*)d_ws;
  ushort_t* xzb  = (ushort_t*)(ws);                       //   0-32 MB (bf16)
  ushort_t* u    = (ushort_t*)(ws + ((size_t)32  << 20)); //  32-48 (bf16)
  float*    dy   = (float*)   (ws + ((size_t)48  << 20)); //  48-80 (delta f32)
  float*    BC   = (float*)   (ws + ((size_t)80  << 20)); //  80-80.5
  float*    hEnd = (float*)   (ws + ((size_t)81  << 20)); //  81-89
  float*    sumD = (float*)   (ws + ((size_t)89  << 20)); //  89-89.5
  ushort_t* xb   = (ushort_t*)(ws + ((size_t)90  << 20)); //  90-98
  ushort_t* WiT  = (ushort_t*)(ws + ((size_t)98  << 20)); //  98-106
  ushort_t* WdT  = (ushort_t*)(ws + ((size_t)106 << 20)); // 106-110
  ushort_t* WoT  = (ushort_t*)(ws + ((size_t)110 << 20)); // 110-114
  ushort_t* yb   = (ushort_t*)(ws + ((size_t)114 << 20)); // 114-130

  // 0. conversions
  cvt_bf16_kernel<<<(ROWS * D_MODEL / 4) / 256, 256, 0, stream>>>(
      x, xb, ROWS * D_MODEL / 4);
  transpose_bf16_kernel<<<dim3(2 * D_INNER / 32, D_MODEL / 32), 256, 0,
                          stream>>>(W_in, WiT, D_MODEL, 2 * D_INNER);
  transpose_bf16_kernel<<<dim3(D_INNER / 32, D_MODEL / 32), 256, 0, stream>>>(
      W_delta, WdT, D_MODEL, D_INNER);
  transpose_bf16_kernel<<<dim3(D_MODEL / 32, D_INNER / 32), 256, 0, stream>>>(
      W_out, WoT, D_INNER, D_MODEL);

  // 1. xz = x @ W_in  (bf16 out)
  gemm_mfma<EPI_NONE, 1><<<dim3((2 * D_INNER) / 128, ROWS / 128), 256, 0,
                           stream>>>(xb, WiT, xzb, ROWS, 2 * D_INNER, D_MODEL,
                                     nullptr, nullptr, nullptr);
  // 2. delta = softplus(x @ W_delta + b) * exp(-alpha*sigma2)  (f32 out)
  gemm_mfma<EPI_DELTA, 0><<<dim3(D_INNER / 128, ROWS / 128), 256, 0, stream>>>(
      xb, WdT, dy, ROWS, D_INNER, D_MODEL, b_delta, sigma2, alpha);
  // 3+4. u = silu(conv(xz[:, :2048])); BC = u @ W_xproj[:, :32]
  conv_xproj_kernel<<<dim3(T_LEN / 8, B_SZ), 256, 0, stream>>>(
      xzb, conv_w, conv_b, W_xproj, u, BC);
  // 5-7. chunked scan
  scan1_kernel<<<dim3(D_INNER / 256, B_SZ, NCHUNK), 256, 0, stream>>>(
      dy, u, BC, A_log, hEnd, sumD);
  scan2_kernel<<<(B_SZ * D_INNER * D_STATE) / 256, 256, 0, stream>>>(A_log,
                                                                     hEnd, sumD);
  scan3_kernel<<<dim3(D_INNER / 256, B_SZ, NCHUNK), 256, 0, stream>>>(
      dy, u, BC, A_log, hEnd, xzb, D_param, yb);
  // 8. out = y @ W_out  (f32 out)
  gemm_mfma<EPI_NONE, 0><<<dim3(D_MODEL / 128, ROWS / 128), 256, 0, stream>>>(
      yb, WoT, out, ROWS, D_MODEL, D_INNER, nullptr, nullptr, nullptr);
}